// Round 7
// baseline (329.075 us; speedup 1.0000x reference)
//
#include <hip/hip_runtime.h>

// WordAttention: B=8, S=2048, D_IN=D_H=512, fp32 in/out.
// R14: ring-3 phase engine at R11's PROVEN register budget.
// R12/R13 post-mortem: full Q hoist (qf[2][16]) needs ~240 unified regs >
// 256 cap at 2 waves/SIMD; allocator stuck at 128 arch + spill (two
// occupancy-attr attempts no-op'd). So: keep R11's layout (qf[2][8] hoist +
// Qh 32KB LDS, 128 VGPR, zero scratch) and upgrade the ENGINE only:
//  - Ring-3 staging (3x32KB): slot written at p holds data(p+1); its last
//    reader ran at compute(p-2), ordered by barrier(p-1) -> ONE barrier per
//    phase, no post-compute lgkm drain (except Ps handoff, 1/kt).
//  - slot = p mod 3: compile-time via 3-kt (24-phase) macro unroll; 16 kt =
//    5 macro iters + tail kt=15 (p=120 = 0 mod 3 -> reuses row-0 slots).
//  - vmcnt: issue 4 loads for p+1, wait vmcnt(4) (drain p's, keep p+1's);
//    tail phase vmcnt(0).
// Numerics unchanged (verified R8-R13): unnormalized p=exp(s) bf16
// (|s|<~45<<88), no online max; rowsum shuffle+LDS reduce; normalize last.
// LDS: 3x32 stage + 32 Qh + 16 Ps + 1 rsw = 145KB (1 block/CU).

typedef __attribute__((ext_vector_type(8))) _Float16 f16x8;
typedef __attribute__((ext_vector_type(8))) short bf16x8;
typedef __attribute__((ext_vector_type(4))) float f32x4;

__device__ __forceinline__ unsigned short f2h(float f) {
  _Float16 h = (_Float16)f;
  return *(unsigned short*)&h;
}
__device__ __forceinline__ unsigned short f2bf(float f) {
  unsigned int u = __float_as_uint(f);
  unsigned int r = (u + 0x7fffu + ((u >> 16) & 1u)) >> 16;
  return (unsigned short)r;
}
__device__ __forceinline__ float bf2f(unsigned short h) {
  return __uint_as_float(((unsigned int)h) << 16);
}

__device__ __forceinline__ void load_lds16(const void* g, void* l) {
  __builtin_amdgcn_global_load_lds(
      (const __attribute__((address_space(1))) unsigned int*)g,
      (__attribute__((address_space(3))) unsigned int*)l, 16, 0, 0);
}

// ---- x fp32 -> fp16 ----
__global__ __launch_bounds__(256) void convx_kernel(const float* __restrict__ x,
                                                    unsigned short* __restrict__ xh) {
  int i = blockIdx.x * 256 + threadIdx.x;
  float4 v = ((const float4*)x)[i];
  union { unsigned short h[4]; short4 s4; } u;
  u.h[0] = f2h(v.x); u.h[1] = f2h(v.y); u.h[2] = f2h(v.z); u.h[3] = f2h(v.w);
  ((short4*)xh)[i] = u.s4;
}

// ---- W [d][h] fp32 -> Wt [h][d] fp16; z = 0,1,2 selects Wq/Wk/Wv ----
__global__ __launch_bounds__(256) void convw_kernel(
    const float* __restrict__ W0, const float* __restrict__ W1,
    const float* __restrict__ W2, unsigned short* __restrict__ Wt) {
  const float* W = (blockIdx.z == 0) ? W0 : (blockIdx.z == 1) ? W1 : W2;
  unsigned short* t = Wt + (size_t)blockIdx.z * 512 * 512;
  __shared__ float tile[32][33];
  int tx = threadIdx.x, ty = threadIdx.y;  // 32 x 8
  int h0 = blockIdx.x * 32, d0 = blockIdx.y * 32;
  for (int i = ty; i < 32; i += 8) tile[i][tx] = W[(long)(d0 + i) * 512 + h0 + tx];
  __syncthreads();
  for (int i = ty; i < 32; i += 8)
    t[(long)(h0 + i) * 512 + d0 + tx] = f2h(tile[tx][i]);
}

// ---- fused QKV projection: [16384,512] x [512,1536]^T + bias.
//      cols 0..511 -> Qo fp16; 512..1023 -> Ko fp16;
//      1024..1535 -> V tiled bf16: Vt[b][s/32][d][s%32].
__global__ __launch_bounds__(256) void gemm_qkv_kernel(
    const unsigned short* __restrict__ A,   // xh [16384][512] fp16
    const unsigned short* __restrict__ Bt,  // Wt [1536][512] fp16
    unsigned short* __restrict__ Qo, unsigned short* __restrict__ Ko,
    unsigned short* __restrict__ VTo,
    const float* __restrict__ bq, const float* __restrict__ bk,
    const float* __restrict__ bv) {
  __shared__ alignas(16) unsigned short As[128 * 32];
  __shared__ alignas(16) unsigned short Bs[128 * 32];
  const int t = threadIdx.x;
  const long long bm = (long long)blockIdx.x * 128;
  const long long bn = (long long)blockIdx.y * 128;

  const int ar = t >> 2;
  const int ac = (t & 3) * 8;

  f32x4 acc[4][4];
#pragma unroll
  for (int i = 0; i < 4; i++)
#pragma unroll
    for (int j = 0; j < 4; j++) acc[i][j] = {0.f, 0.f, 0.f, 0.f};

  const int lane = t & 63;
  const int wave = t >> 6;
  const int wm = (wave & 1) * 64;
  const int wn = (wave >> 1) * 64;
  const int fm = lane & 15;
  const int k8 = (lane >> 4) * 8;

  for (int kt = 0; kt < 512; kt += 32) {
#pragma unroll
    for (int r = 0; r < 2; r++)
      load_lds16(A + (bm + r * 64 + ar) * 512 + kt + ac, &As[r * 2048 + t * 8]);
#pragma unroll
    for (int r = 0; r < 2; r++)
      load_lds16(Bt + (bn + r * 64 + ar) * 512 + kt + ac, &Bs[r * 2048 + t * 8]);
    __syncthreads();

    f16x8 af[4], bfr[4];
#pragma unroll
    for (int i = 0; i < 4; i++)
      af[i] = *(const f16x8*)&As[(wm + i * 16 + fm) * 32 + k8];
#pragma unroll
    for (int j = 0; j < 4; j++)
      bfr[j] = *(const f16x8*)&Bs[(wn + j * 16 + fm) * 32 + k8];
#pragma unroll
    for (int i = 0; i < 4; i++)
#pragma unroll
      for (int j = 0; j < 4; j++)
        acc[i][j] = __builtin_amdgcn_mfma_f32_16x16x32_f16(af[i], bfr[j], acc[i][j], 0, 0, 0);
    __syncthreads();
  }

  const int crow = (lane >> 4) * 4;  // C/D: col=lane&15, row=(lane>>4)*4+reg
  const int ccol = lane & 15;
#pragma unroll
  for (int j = 0; j < 4; j++) {
    const long long col = bn + wn + j * 16 + ccol;
    float bias = (col < 512) ? bq[col] : (col < 1024) ? bk[col - 512] : bv[col - 1024];
#pragma unroll
    for (int i = 0; i < 4; i++) {
      const long long row0 = bm + wm + i * 16 + crow;
      if (col >= 1024) {
        const long long b = row0 >> 11;
        const long long s = row0 & 2047;
        const long long dcol = col - 1024;
        union { unsigned short h[4]; short4 s4; } u;
#pragma unroll
        for (int r = 0; r < 4; r++) u.h[r] = f2bf(acc[i][j][r] + bias);  // V -> bf16
        // tiled: Vt[b][s/32][d][s%32]; short4 spans 4 consecutive s in-block
        *(short4*)(VTo + (((b * 64 + (s >> 5)) * 512 + dcol) * 32 + (s & 31))) = u.s4;
      } else {
        unsigned short* dst = (col < 512) ? (Qo + row0 * 512 + col)
                                          : (Ko + row0 * 512 + (col - 512));
#pragma unroll
        for (int r = 0; r < 4; r++) dst[(size_t)r * 512] = f2h(acc[i][j][r] + bias);
      }
    }
  }
}

// ---- phase bodies (U compile-time) ----
template <int U>
__device__ __forceinline__ void qkt_body(const unsigned short* cur, const unsigned short* Qh,
                                         const f16x8 (&qf)[2][8], f32x4 (&sacc)[2][2],
                                         int kg, int qh, int fm, int g, int swz) {
  __builtin_amdgcn_s_setprio(1);
#pragma unroll
  for (int s = 0; s < 4; ++s) {
    const int off = (s * 64 + g * 16) ^ swz;
    const f16x8 a0 = *(const f16x8*)((const char*)cur + (kg * 32 + fm) * 256 + off);
    const f16x8 a1 = *(const f16x8*)((const char*)cur + (kg * 32 + 16 + fm) * 256 + off);
    f16x8 b0, b1;
    if constexpr (U < 2) {
      b0 = qf[0][U * 4 + s];
      b1 = qf[1][U * 4 + s];
    } else {
      const int dz = (g * 16 + ((U - 2) * 4 + s) * 64) ^ swz;
      b0 = *(const f16x8*)((const char*)Qh + (qh * 32 + fm) * 512 + dz);
      b1 = *(const f16x8*)((const char*)Qh + (qh * 32 + 16 + fm) * 512 + dz);
    }
    sacc[0][0] = __builtin_amdgcn_mfma_f32_16x16x32_f16(a0, b0, sacc[0][0], 0, 0, 0);
    sacc[0][1] = __builtin_amdgcn_mfma_f32_16x16x32_f16(a0, b1, sacc[0][1], 0, 0, 0);
    sacc[1][0] = __builtin_amdgcn_mfma_f32_16x16x32_f16(a1, b0, sacc[1][0], 0, 0, 0);
    sacc[1][1] = __builtin_amdgcn_mfma_f32_16x16x32_f16(a1, b1, sacc[1][1], 0, 0, 0);
  }
  __builtin_amdgcn_s_setprio(0);
}

__device__ __forceinline__ void exp_ps(const f32x4 (&sacc)[2][2], unsigned short* Ps,
                                       float& psum0, float& psum1,
                                       int kg, int qh, int fm, int g, int swz) {
#pragma unroll
  for (int i = 0; i < 2; ++i)
#pragma unroll
    for (int j = 0; j < 2; ++j) {
      const int q = qh * 32 + j * 16 + fm;
      const int k2 = (kg * 32 + i * 16 + g * 4) * 2;
      union { unsigned short h[4]; short4 s4; } uu;
      float s0 = 0.f;
#pragma unroll
      for (int r = 0; r < 4; ++r) {
        const unsigned short pb = f2bf(__expf(sacc[i][j][r]));
        uu.h[r] = pb; s0 += bf2f(pb);
      }
      if (j == 0) psum0 += s0; else psum1 += s0;
      *(short4*)((char*)Ps + q * 256 + (k2 ^ swz)) = uu.s4;
    }
}

template <int JU>
__device__ __forceinline__ void pv_body(const unsigned short* cur, const unsigned short* Ps,
                                        f32x4 (&oacc)[2][8],
                                        int kg, int qh, int fm, int g, int swz) {
  const bf16x8 p0 = *(const bf16x8*)((const char*)Ps +
      (qh * 32 + fm) * 256 + ((JU * 64 + g * 16) ^ swz));
  const bf16x8 p1 = *(const bf16x8*)((const char*)Ps +
      (qh * 32 + 16 + fm) * 256 + ((JU * 64 + g * 16) ^ swz));
  __builtin_amdgcn_s_setprio(1);
#pragma unroll
  for (int jj = 0; jj < 8; ++jj) {
    const bf16x8 vf = *(const bf16x8*)((const char*)cur +
        (kg * 128 + jj * 16 + fm) * 64 + g * 16);
    oacc[0][jj] = __builtin_amdgcn_mfma_f32_16x16x32_bf16(p0, vf, oacc[0][jj], 0, 0, 0);
    oacc[1][jj] = __builtin_amdgcn_mfma_f32_16x16x32_bf16(p1, vf, oacc[1][jj], 0, 0, 0);
  }
  __builtin_amdgcn_s_setprio(0);
}

// One phase: stage data(p+1) into slot SN, counted wait, ONE barrier, compute
// slot SC. U,SC,SN are literals; KT runtime; LAST=1 only for kt=15.
#define PHASE(U, SC, SN, KT, LAST)                                             \
  do {                                                                         \
    unsigned short* nx = SB + (SN) * 16384;                                    \
    if ((U) < 3) {                                                             \
      const unsigned short* gs = Kb + (size_t)(KT) * 65536 + ((U) + 1) * 128;  \
      load_lds16(gs + ksrc[0], nx + sdst[0]);                                  \
      load_lds16(gs + ksrc[1], nx + sdst[1]);                                  \
      load_lds16(gs + ksrc[2], nx + sdst[2]);                                  \
      load_lds16(gs + ksrc[3], nx + sdst[3]);                                  \
    } else if ((U) < 7) {                                                      \
      const unsigned short* gs = Vb + ((size_t)(KT) * 4 + (U) - 3) * 16384;    \
      load_lds16(gs + sdst[0], nx + sdst[0]);                                  \
      load_lds16(gs + sdst[1], nx + sdst[1]);                                  \
      load_lds16(gs + sdst[2], nx + sdst[2]);                                  \
      load_lds16(gs + sdst[3], nx + sdst[3]);                                  \
    } else if (!(LAST)) {                                                      \
      const unsigned short* gs = Kb + (size_t)((KT) + 1) * 65536;              \
      load_lds16(gs + ksrc[0], nx + sdst[0]);                                  \
      load_lds16(gs + ksrc[1], nx + sdst[1]);                                  \
      load_lds16(gs + ksrc[2], nx + sdst[2]);                                  \
      load_lds16(gs + ksrc[3], nx + sdst[3]);                                  \
    }                                                                          \
    if ((LAST) && (U) == 7) asm volatile("s_waitcnt vmcnt(0)" ::: "memory");   \
    else                    asm volatile("s_waitcnt vmcnt(4)" ::: "memory");   \
    __builtin_amdgcn_s_barrier();                                              \
    __builtin_amdgcn_sched_barrier(0);                                         \
    {                                                                          \
      const unsigned short* cur = SB + (SC) * 16384;                           \
      if ((U) == 0) {                                                          \
        sacc[0][0] = {0.f, 0.f, 0.f, 0.f}; sacc[0][1] = {0.f, 0.f, 0.f, 0.f}; \
        sacc[1][0] = {0.f, 0.f, 0.f, 0.f}; sacc[1][1] = {0.f, 0.f, 0.f, 0.f}; \
      }                                                                        \
      if ((U) < 4) {                                                           \
        qkt_body<((U) < 4 ? (U) : 0)>(cur, Qh, qf, sacc, kg, qh, fm, g, swz);  \
        if ((U) == 3) {                                                        \
          exp_ps(sacc, Ps, psum0, psum1, kg, qh, fm, g, swz);                  \
          asm volatile("s_waitcnt lgkmcnt(0)" ::: "memory");                   \
        }                                                                      \
      } else {                                                                 \
        pv_body<((U) >= 4 ? (U) - 4 : 0)>(cur, Ps, oacc, kg, qh, fm, g, swz);  \
      }                                                                        \
    }                                                                          \
  } while (0)

// ---- fused attention: out[b][q][d] = (sum_k exp(QK^T) V) / rowsum.
// grid 256 (b=bid&7, q-tile=bid>>3: 64 q-rows), 512 threads (8 waves).
// Wave w: qh=w&1 (32-q half), kg=w>>1 (k-group in QKT / d-quarter in PV).
__global__ __launch_bounds__(512, 2) void attn_fused_kernel(
    const unsigned short* __restrict__ Qg,  // [8][2048][512] fp16
    const unsigned short* __restrict__ Kg,  // [8][2048][512] fp16
    const unsigned short* __restrict__ Vt,  // [8][64][512][32] bf16 tiled
    float* __restrict__ out) {              // [8][2048][512] fp32
  __shared__ alignas(16) unsigned short SB[3 * 16384];  // 3x32KB stage ring
  __shared__ alignas(16) unsigned short Qh[16384];      // Q high-d [64q][256d] swz
  __shared__ alignas(16) unsigned short Ps[8192];       // P [64q][128k] bf16 swz
  __shared__ float rsw[4][64];

  const int t = threadIdx.x;
  const int lane = t & 63;
  const int w = t >> 6;
  const int fm = lane & 15;
  const int g = lane >> 4;
  const int qh = w & 1;
  const int kg = w >> 1;
  const int b = blockIdx.x & 7;
  const int q0 = (blockIdx.x >> 3) << 6;

  const unsigned short* Qb = Qg + ((size_t)b * 2048 + q0) * 512;
  const unsigned short* Kb = Kg + (size_t)b * 2048 * 512;
  const unsigned short* Vb = Vt + (size_t)b * 2048 * 512;

  // per-thread staging offsets (4 rounds x 512 thr x 16B = 32KB/unit)
  int ksrc[4], qsrc[4]; unsigned int sdst[4];
#pragma unroll
  for (int r = 0; r < 4; ++r) {
    const int L = r * 8192 + t * 16;  // byte offset within a 32KB unit
    sdst[r] = L >> 1;
    const int kr = L >> 8;            // K unit rows (256 B)
    ksrc[r] = kr * 512 + (((L & 255) ^ ((kr & 7) << 4)) >> 1);
    const int qr = L >> 9;            // Q rows (512 B)
    qsrc[r] = qr * 512 + (((L & 511) ^ ((qr & 7) << 4)) >> 1);
  }

  // ---- prologue: stage Qlow -> SB slot0, Qhigh -> Qh ----
#pragma unroll
  for (int r = 0; r < 4; ++r) load_lds16(Qb + qsrc[r], SB + sdst[r]);
#pragma unroll
  for (int r = 0; r < 4; ++r) load_lds16(Qb + 256 + qsrc[r], Qh + sdst[r]);
  asm volatile("s_waitcnt vmcnt(0)" ::: "memory");
  __builtin_amdgcn_s_barrier();
  __builtin_amdgcn_sched_barrier(0);

  const int swz = (fm & 7) << 4;  // row&7 == fm&7 for all frag rows used
  f16x8 qf[2][8];  // Q hoist d<256: [q-frag][d-chunk], 64 VGPRs
#pragma unroll
  for (int j = 0; j < 2; ++j) {
    const char* qbase = (const char*)SB + (qh * 32 + j * 16 + fm) * 512;
#pragma unroll
    for (int ds = 0; ds < 8; ++ds)
      qf[j][ds] = *(const f16x8*)(qbase + ((g * 16 + ds * 64) ^ swz));
  }
  asm volatile("s_waitcnt lgkmcnt(0)" ::: "memory");
  __builtin_amdgcn_s_barrier();
  __builtin_amdgcn_sched_barrier(0);

  // stage K[0][0] -> slot 0 (consumed by phase p=0)
#pragma unroll
  for (int r = 0; r < 4; ++r) load_lds16(Kb + ksrc[r], SB + sdst[r]);

  f32x4 oacc[2][8];
#pragma unroll
  for (int i = 0; i < 2; ++i)
#pragma unroll
    for (int jj = 0; jj < 8; ++jj) oacc[i][jj] = {0.f, 0.f, 0.f, 0.f};
  float psum0 = 0.f, psum1 = 0.f;
  f32x4 sacc[2][2];

  // ---- main loop: 5 macro-iters x 3 kt (24 phases, slot = p mod 3) ----
  for (int m = 0; m < 5; ++m) {
    const int k0 = 3 * m;
    // kt = k0 (kt mod 3 == 0): SC = u%3
    PHASE(0, 0, 1, k0, 0); PHASE(1, 1, 2, k0, 0); PHASE(2, 2, 0, k0, 0); PHASE(3, 0, 1, k0, 0);
    PHASE(4, 1, 2, k0, 0); PHASE(5, 2, 0, k0, 0); PHASE(6, 0, 1, k0, 0); PHASE(7, 1, 2, k0, 0);
    // kt = k0+1 (mod 3 == 1): SC = (u+2)%3
    PHASE(0, 2, 0, k0 + 1, 0); PHASE(1, 0, 1, k0 + 1, 0); PHASE(2, 1, 2, k0 + 1, 0); PHASE(3, 2, 0, k0 + 1, 0);
    PHASE(4, 0, 1, k0 + 1, 0); PHASE(5, 1, 2, k0 + 1, 0); PHASE(6, 2, 0, k0 + 1, 0); PHASE(7, 0, 1, k0 + 1, 0);
    // kt = k0+2 (mod 3 == 2): SC = (u+1)%3
    PHASE(0, 1, 2, k0 + 2, 0); PHASE(1, 2, 0, k0 + 2, 0); PHASE(2, 0, 1, k0 + 2, 0); PHASE(3, 1, 2, k0 + 2, 0);
    PHASE(4, 2, 0, k0 + 2, 0); PHASE(5, 0, 1, k0 + 2, 0); PHASE(6, 1, 2, k0 + 2, 0); PHASE(7, 2, 0, k0 + 2, 0);
  }
  // ---- tail kt = 15 (p=120..127, 120 mod 3 == 0 -> row-0 slots) ----
  PHASE(0, 0, 1, 15, 0); PHASE(1, 1, 2, 15, 0); PHASE(2, 2, 0, 15, 0); PHASE(3, 0, 1, 15, 0);
  PHASE(4, 1, 2, 15, 0); PHASE(5, 2, 0, 15, 0); PHASE(6, 0, 1, 15, 0); PHASE(7, 1, 2, 15, 1);

  // ---- rowsum reduce: quads (shuffle) then k-groups (LDS) ----
  psum0 += __shfl_xor(psum0, 16); psum0 += __shfl_xor(psum0, 32);
  psum1 += __shfl_xor(psum1, 16); psum1 += __shfl_xor(psum1, 32);
  if (g == 0) {
    rsw[kg][qh * 32 + fm] = psum0;
    rsw[kg][qh * 32 + 16 + fm] = psum1;
  }
  __syncthreads();

  // ---- normalize + store: row q = qh*32+i*16+g*4+r, col d = kg*128+jj*16+fm
  float* ob = out + ((size_t)b * 2048 + q0) * 512;
#pragma unroll
  for (int i = 0; i < 2; ++i) {
    float inv[4];
#pragma unroll
    for (int r = 0; r < 4; ++r) {
      const int q = qh * 32 + i * 16 + g * 4 + r;
      inv[r] = 1.0f / (rsw[0][q] + rsw[1][q] + rsw[2][q] + rsw[3][q]);
    }
#pragma unroll
    for (int jj = 0; jj < 8; ++jj) {
      const int d = kg * 128 + jj * 16 + fm;
#pragma unroll
      for (int r = 0; r < 4; ++r)
        ob[(size_t)(qh * 32 + i * 16 + g * 4 + r) * 512 + d] = oacc[i][jj][r] * inv[r];
    }
  }
}

extern "C" void kernel_launch(void* const* d_in, const int* in_sizes, int n_in,
                              void* d_out, int out_size, void* d_ws, size_t ws_size,
                              hipStream_t stream) {
  const float* x  = (const float*)d_in[0];
  const float* Wq = (const float*)d_in[1];
  const float* bq = (const float*)d_in[2];
  const float* Wk = (const float*)d_in[3];
  const float* bk = (const float*)d_in[4];
  const float* Wv = (const float*)d_in[5];
  const float* bv = (const float*)d_in[6];
  float* out = (float*)d_out;

  const size_t SZ = (size_t)16384 * 512 * 2;  // 16.78 MB (half-prec [16384,512])
  char* p = (char*)d_ws;
  unsigned short* xh = (unsigned short*)p; p += SZ;
  unsigned short* Wt = (unsigned short*)p; p += (size_t)3 * 512 * 512 * 2;
  unsigned short* Qb = (unsigned short*)p; p += SZ;              // fp16 [token][512]
  unsigned short* Kb = (unsigned short*)p; p += SZ;              // fp16 [token][512]
  unsigned short* VT = (unsigned short*)p; p += SZ;              // bf16 tiled [b][s/32][d][s%32]

  convx_kernel<<<8192, 256, 0, stream>>>(x, xh);
  convw_kernel<<<dim3(16, 16, 3), dim3(32, 8), 0, stream>>>(Wq, Wk, Wv, Wt);
  gemm_qkv_kernel<<<dim3(128, 12), 256, 0, stream>>>(xh, Wt, Qb, Kb, VT, bq, bk, bv);
  attn_fused_kernel<<<256, 512, 0, stream>>>(Qb, Kb, VT, out);
}

// Round 8
// 246.126 us; speedup vs baseline: 1.3370x; 1.3370x over previous
//
#include <hip/hip_runtime.h>

// WordAttention: B=8, S=2048, D_IN=D_H=512, fp32 in/out.
// R15 = R11's PROVEN engine (125us, 128 VGPR, zero scratch) + V-read
// bank-conflict fix (single variable).
// R12-R14 post-mortem: any register demand above R11's level spills
// (allocator pinned at 128 arch VGPRs; occupancy attrs no-op; macro-unroll
// catastrophic: 350MB scratch). So the engine stays R11: 2x32KB ping-pong,
// 1-phase lead, vmcnt(4) counted waits, 2 barriers/phase, runtime loop.
// NEW: V LDS layout XOR-swizzle. Old V read (byte = d*64 + g*16, 64-B rows)
// put each 16-lane quarter on 2 of 8 slots -> 8-way conflict (2.9x, m136)
// on all 8 V reads per PV phase = the measured 12.2M SQ_LDS_BANK_CONFLICT.
// Fix: byte ^= ((d>>1)&7)<<4, applied BOTH sides (rule 21): at the qkv
// V-epilogue global write (staging is identity copy -> pre-swizzled global)
// and at the PV read (folds to per-thread const vswz=((fm>>1)&7)<<4).
// After: slot = ((fm&1)<<2|g) ^ ((fm>>1)&7) -> all 8 slots 2x = free.
// Numerics unchanged (verified R8-R14): unnormalized p=exp(s) bf16
// (|s|<~45<<88), no online max; rowsum shuffle+LDS reduce; normalize last.

typedef __attribute__((ext_vector_type(8))) _Float16 f16x8;
typedef __attribute__((ext_vector_type(8))) short bf16x8;
typedef __attribute__((ext_vector_type(4))) float f32x4;

__device__ __forceinline__ unsigned short f2h(float f) {
  _Float16 h = (_Float16)f;
  return *(unsigned short*)&h;
}
__device__ __forceinline__ unsigned short f2bf(float f) {
  unsigned int u = __float_as_uint(f);
  unsigned int r = (u + 0x7fffu + ((u >> 16) & 1u)) >> 16;
  return (unsigned short)r;
}
__device__ __forceinline__ float bf2f(unsigned short h) {
  return __uint_as_float(((unsigned int)h) << 16);
}

__device__ __forceinline__ void load_lds16(const void* g, void* l) {
  __builtin_amdgcn_global_load_lds(
      (const __attribute__((address_space(1))) unsigned int*)g,
      (__attribute__((address_space(3))) unsigned int*)l, 16, 0, 0);
}

// ---- x fp32 -> fp16 ----
__global__ __launch_bounds__(256) void convx_kernel(const float* __restrict__ x,
                                                    unsigned short* __restrict__ xh) {
  int i = blockIdx.x * 256 + threadIdx.x;
  float4 v = ((const float4*)x)[i];
  union { unsigned short h[4]; short4 s4; } u;
  u.h[0] = f2h(v.x); u.h[1] = f2h(v.y); u.h[2] = f2h(v.z); u.h[3] = f2h(v.w);
  ((short4*)xh)[i] = u.s4;
}

// ---- W [d][h] fp32 -> Wt [h][d] fp16; z = 0,1,2 selects Wq/Wk/Wv ----
__global__ __launch_bounds__(256) void convw_kernel(
    const float* __restrict__ W0, const float* __restrict__ W1,
    const float* __restrict__ W2, unsigned short* __restrict__ Wt) {
  const float* W = (blockIdx.z == 0) ? W0 : (blockIdx.z == 1) ? W1 : W2;
  unsigned short* t = Wt + (size_t)blockIdx.z * 512 * 512;
  __shared__ float tile[32][33];
  int tx = threadIdx.x, ty = threadIdx.y;  // 32 x 8
  int h0 = blockIdx.x * 32, d0 = blockIdx.y * 32;
  for (int i = ty; i < 32; i += 8) tile[i][tx] = W[(long)(d0 + i) * 512 + h0 + tx];
  __syncthreads();
  for (int i = ty; i < 32; i += 8)
    t[(long)(h0 + i) * 512 + d0 + tx] = f2h(tile[tx][i]);
}

// ---- fused QKV projection: [16384,512] x [512,1536]^T + bias.
//      cols 0..511 -> Qo fp16; 512..1023 -> Ko fp16;
//      1024..1535 -> V tiled+swizzled bf16 (32KB unit = [b][s/32], within:
//      byte L = d*64 + (s%32)*2, stored at L ^ ((d>>1)&7)<<4).
__global__ __launch_bounds__(256) void gemm_qkv_kernel(
    const unsigned short* __restrict__ A,   // xh [16384][512] fp16
    const unsigned short* __restrict__ Bt,  // Wt [1536][512] fp16
    unsigned short* __restrict__ Qo, unsigned short* __restrict__ Ko,
    unsigned short* __restrict__ VTo,
    const float* __restrict__ bq, const float* __restrict__ bk,
    const float* __restrict__ bv) {
  __shared__ alignas(16) unsigned short As[128 * 32];
  __shared__ alignas(16) unsigned short Bs[128 * 32];
  const int t = threadIdx.x;
  const long long bm = (long long)blockIdx.x * 128;
  const long long bn = (long long)blockIdx.y * 128;

  const int ar = t >> 2;
  const int ac = (t & 3) * 8;

  f32x4 acc[4][4];
#pragma unroll
  for (int i = 0; i < 4; i++)
#pragma unroll
    for (int j = 0; j < 4; j++) acc[i][j] = {0.f, 0.f, 0.f, 0.f};

  const int lane = t & 63;
  const int wave = t >> 6;
  const int wm = (wave & 1) * 64;
  const int wn = (wave >> 1) * 64;
  const int fm = lane & 15;
  const int k8 = (lane >> 4) * 8;

  for (int kt = 0; kt < 512; kt += 32) {
#pragma unroll
    for (int r = 0; r < 2; r++)
      load_lds16(A + (bm + r * 64 + ar) * 512 + kt + ac, &As[r * 2048 + t * 8]);
#pragma unroll
    for (int r = 0; r < 2; r++)
      load_lds16(Bt + (bn + r * 64 + ar) * 512 + kt + ac, &Bs[r * 2048 + t * 8]);
    __syncthreads();

    f16x8 af[4], bfr[4];
#pragma unroll
    for (int i = 0; i < 4; i++)
      af[i] = *(const f16x8*)&As[(wm + i * 16 + fm) * 32 + k8];
#pragma unroll
    for (int j = 0; j < 4; j++)
      bfr[j] = *(const f16x8*)&Bs[(wn + j * 16 + fm) * 32 + k8];
#pragma unroll
    for (int i = 0; i < 4; i++)
#pragma unroll
      for (int j = 0; j < 4; j++)
        acc[i][j] = __builtin_amdgcn_mfma_f32_16x16x32_f16(af[i], bfr[j], acc[i][j], 0, 0, 0);
    __syncthreads();
  }

  const int crow = (lane >> 4) * 4;  // C/D: col=lane&15, row=(lane>>4)*4+reg
  const int ccol = lane & 15;
#pragma unroll
  for (int j = 0; j < 4; j++) {
    const long long col = bn + wn + j * 16 + ccol;
    float bias = (col < 512) ? bq[col] : (col < 1024) ? bk[col - 512] : bv[col - 1024];
#pragma unroll
    for (int i = 0; i < 4; i++) {
      const long long row0 = bm + wm + i * 16 + crow;
      if (col >= 1024) {
        const long long b = row0 >> 11;
        const long long s = row0 & 2047;
        const long long dcol = col - 1024;
        union { unsigned short h[4]; short4 s4; } u;
#pragma unroll
        for (int r = 0; r < 4; r++) u.h[r] = f2bf(acc[i][j][r] + bias);  // V -> bf16
        // swizzled tiled V: unit=(b,s/32) 32KB; L = d*64+(s%32)*2, XOR'd.
        // (s&31)*2 mod 16 in {0,8}: 8-B store stays within one 16-B slot.
        const long long unit = b * 64 + (s >> 5);
        const int L = ((int)dcol * 64 + (int)(s & 31) * 2) ^ ((((int)dcol >> 1) & 7) << 4);
        *(short4*)((char*)VTo + unit * 32768 + L) = u.s4;
      } else {
        unsigned short* dst = (col < 512) ? (Qo + row0 * 512 + col)
                                          : (Ko + row0 * 512 + (col - 512));
#pragma unroll
        for (int r = 0; r < 4; r++) dst[(size_t)r * 512] = f2h(acc[i][j][r] + bias);
      }
    }
  }
}

// ---- fused attention: out[b][q][d] = (sum_k exp(QK^T) V) / rowsum.
// grid 256 (b=bid&7, q-tile=bid>>3: 64 q-rows), 512 threads (8 waves).
// Wave w: qh=w&1 (32-q half), kg=w>>1 (k-group in QKT / d-quarter in PV).
__global__ __launch_bounds__(512, 2) void attn_fused_kernel(
    const unsigned short* __restrict__ Qg,  // [8][2048][512] fp16
    const unsigned short* __restrict__ Kg,  // [8][2048][512] fp16
    const unsigned short* __restrict__ Vt,  // [8][64] x 32KB swizzled V units
    float* __restrict__ out) {              // [8][2048][512] fp32
  __shared__ alignas(16) unsigned short SB[2][16384];  // 2x32KB stage ping-pong
  __shared__ alignas(16) unsigned short Qh[16384];     // Q high-d [64q][256d] swz
  __shared__ alignas(16) unsigned short Ps[8192];      // P [64q][128k] bf16 swz
  __shared__ float rsw[4][64];

  const int t = threadIdx.x;
  const int lane = t & 63;
  const int w = t >> 6;
  const int fm = lane & 15;
  const int g = lane >> 4;
  const int qh = w & 1;
  const int kg = w >> 1;
  const int b = blockIdx.x & 7;
  const int q0 = (blockIdx.x >> 3) << 6;

  const unsigned short* Qb = Qg + ((size_t)b * 2048 + q0) * 512;
  const unsigned short* Kb = Kg + (size_t)b * 2048 * 512;
  const unsigned short* Vb = Vt + (size_t)b * 2048 * 512;

  // per-thread staging offsets (4 rounds x 512 thr x 16B = 32KB/unit)
  int ksrc[4], qsrc[4]; unsigned int sdst[4];
#pragma unroll
  for (int r = 0; r < 4; ++r) {
    const int L = r * 8192 + t * 16;  // byte offset within a 32KB unit
    sdst[r] = L >> 1;
    const int kr = L >> 8;            // K unit rows (256 B)
    ksrc[r] = kr * 512 + (((L & 255) ^ ((kr & 7) << 4)) >> 1);
    const int qr = L >> 9;            // Q rows (512 B)
    qsrc[r] = qr * 512 + (((L & 511) ^ ((qr & 7) << 4)) >> 1);
  }

  // ---- prologue: stage Qlow -> SB0, Qhigh -> Qh; read Q-frags (d<256) to regs
#pragma unroll
  for (int r = 0; r < 4; ++r) load_lds16(Qb + qsrc[r], &SB[0][sdst[r]]);
#pragma unroll
  for (int r = 0; r < 4; ++r) load_lds16(Qb + 256 + qsrc[r], &Qh[sdst[r]]);
  asm volatile("s_waitcnt vmcnt(4)" ::: "memory");  // Qlow landed (Qh may fly)
  __builtin_amdgcn_s_barrier();

  const int swz = (fm & 7) << 4;
  const int vswz = ((fm >> 1) & 7) << 4;  // V-read side of the V swizzle
  f16x8 qf[2][8];
#pragma unroll
  for (int j = 0; j < 2; ++j)
#pragma unroll
    for (int ds = 0; ds < 8; ++ds)
      qf[j][ds] = *(const f16x8*)((const char*)SB[0] +
          (qh * 32 + j * 16 + fm) * 512 + ((g * 16 + ds * 64) ^ swz));
  asm volatile("s_waitcnt lgkmcnt(0)" ::: "memory");
  __builtin_amdgcn_s_barrier();
  // stage K-unit0 of kt0 into SB0 (cur of phase 0)
#pragma unroll
  for (int r = 0; r < 4; ++r) load_lds16(Kb + ksrc[r], &SB[0][sdst[r]]);

  f32x4 oacc[2][8];
#pragma unroll
  for (int i = 0; i < 2; ++i)
#pragma unroll
    for (int jj = 0; jj < 8; ++jj) oacc[i][jj] = {0.f, 0.f, 0.f, 0.f};
  float psum0 = 0.f, psum1 = 0.f;
  f32x4 sacc[2][2];

  for (int kt = 0; kt < 16; ++kt) {
    const size_t kbase = (size_t)kt * 65536;  // kt*128*512 elements
#pragma unroll
    for (int u = 0; u < 8; ++u) {
      unsigned short* cur = SB[u & 1];
      unsigned short* nxt = SB[(u & 1) ^ 1];
      // ---- issue next stage unit (1 phase ahead) ----
      if (u < 3) {
#pragma unroll
        for (int r = 0; r < 4; ++r)
          load_lds16(Kb + kbase + (u + 1) * 128 + ksrc[r], &nxt[sdst[r]]);
      } else if (u < 7) {
        const unsigned short* vs = Vb + (size_t)(kt * 4 + (u - 3)) * 16384;
#pragma unroll
        for (int r = 0; r < 4; ++r) load_lds16(vs + sdst[r], &nxt[sdst[r]]);
      } else if (kt < 15) {
#pragma unroll
        for (int r = 0; r < 4; ++r)
          load_lds16(Kb + kbase + 65536 + ksrc[r], &nxt[sdst[r]]);
      }
      // ---- counted wait: cur's 4 loads done, nxt's 4 stay in flight ----
      if (kt == 15 && u == 7)
        asm volatile("s_waitcnt vmcnt(0)" ::: "memory");
      else
        asm volatile("s_waitcnt vmcnt(4)" ::: "memory");
      __builtin_amdgcn_s_barrier();
      __builtin_amdgcn_sched_barrier(0);

      __builtin_amdgcn_s_setprio(1);
      if (u < 4) {
        // ---- QKT phase: S^T[k 32-grp][q 64] += K-unit_u x Q(d-slice) ----
        if (u == 0) {
          sacc[0][0] = {0.f, 0.f, 0.f, 0.f}; sacc[0][1] = {0.f, 0.f, 0.f, 0.f};
          sacc[1][0] = {0.f, 0.f, 0.f, 0.f}; sacc[1][1] = {0.f, 0.f, 0.f, 0.f};
        }
#pragma unroll
        for (int s = 0; s < 4; ++s) {
          const f16x8 a0 = *(const f16x8*)((const char*)cur +
              (kg * 32 + fm) * 256 + ((g * 16 + s * 64) ^ swz));
          const f16x8 a1 = *(const f16x8*)((const char*)cur +
              (kg * 32 + 16 + fm) * 256 + ((g * 16 + s * 64) ^ swz));
          f16x8 b0, b1;
          if (u < 2) {
            b0 = qf[0][u * 4 + s]; b1 = qf[1][u * 4 + s];
          } else {
            const int dz = (g * 16 + ((u - 2) * 4 + s) * 64) ^ swz;
            b0 = *(const f16x8*)((const char*)Qh + (qh * 32 + fm) * 512 + dz);
            b1 = *(const f16x8*)((const char*)Qh + (qh * 32 + 16 + fm) * 512 + dz);
          }
          sacc[0][0] = __builtin_amdgcn_mfma_f32_16x16x32_f16(a0, b0, sacc[0][0], 0, 0, 0);
          sacc[0][1] = __builtin_amdgcn_mfma_f32_16x16x32_f16(a0, b1, sacc[0][1], 0, 0, 0);
          sacc[1][0] = __builtin_amdgcn_mfma_f32_16x16x32_f16(a1, b0, sacc[1][0], 0, 0, 0);
          sacc[1][1] = __builtin_amdgcn_mfma_f32_16x16x32_f16(a1, b1, sacc[1][1], 0, 0, 0);
        }
        if (u == 3) {
          // exp -> bf16 P (swizzled) + rowsum partials
#pragma unroll
          for (int i = 0; i < 2; ++i)
#pragma unroll
            for (int j = 0; j < 2; ++j) {
              const int q = qh * 32 + j * 16 + fm;
              const int k2 = (kg * 32 + i * 16 + g * 4) * 2;
              union { unsigned short h[4]; short4 s4; } uu;
              float s0 = 0.f;
#pragma unroll
              for (int r = 0; r < 4; ++r) {
                const unsigned short pb = f2bf(__expf(sacc[i][j][r]));
                uu.h[r] = pb; s0 += bf2f(pb);
              }
              if (j == 0) psum0 += s0; else psum1 += s0;
              *(short4*)((char*)Ps + q * 256 + (k2 ^ swz)) = uu.s4;
            }
        }
      } else {
        // ---- PV phase: out[q 32-half][d 128-qtr] += P(k-slice) x V-unit ----
        const int ju = u - 4;
        const bf16x8 p0 = *(const bf16x8*)((const char*)Ps +
            (qh * 32 + fm) * 256 + ((ju * 64 + g * 16) ^ swz));
        const bf16x8 p1 = *(const bf16x8*)((const char*)Ps +
            (qh * 32 + 16 + fm) * 256 + ((ju * 64 + g * 16) ^ swz));
#pragma unroll
        for (int jj = 0; jj < 8; ++jj) {
          const bf16x8 vf = *(const bf16x8*)((const char*)cur +
              ((((kg * 128 + jj * 16 + fm) * 64) + g * 16) ^ vswz));
          oacc[0][jj] = __builtin_amdgcn_mfma_f32_16x16x32_bf16(p0, vf, oacc[0][jj], 0, 0, 0);
          oacc[1][jj] = __builtin_amdgcn_mfma_f32_16x16x32_bf16(p1, vf, oacc[1][jj], 0, 0, 0);
        }
      }
      __builtin_amdgcn_s_setprio(0);
      asm volatile("s_waitcnt lgkmcnt(0)" ::: "memory");  // all my LDS reads done
      __builtin_amdgcn_s_barrier();                        // buf free for overwrite
    }
  }

  // ---- rowsum reduce: quads (shuffle) then k-groups (LDS) ----
  psum0 += __shfl_xor(psum0, 16); psum0 += __shfl_xor(psum0, 32);
  psum1 += __shfl_xor(psum1, 16); psum1 += __shfl_xor(psum1, 32);
  if (g == 0) {
    rsw[kg][qh * 32 + fm] = psum0;
    rsw[kg][qh * 32 + 16 + fm] = psum1;
  }
  __syncthreads();

  // ---- normalize + store: row q = qh*32+i*16+g*4+r, col d = kg*128+jj*16+fm
  float* ob = out + ((size_t)b * 2048 + q0) * 512;
#pragma unroll
  for (int i = 0; i < 2; ++i) {
    float inv[4];
#pragma unroll
    for (int r = 0; r < 4; ++r) {
      const int q = qh * 32 + i * 16 + g * 4 + r;
      inv[r] = 1.0f / (rsw[0][q] + rsw[1][q] + rsw[2][q] + rsw[3][q]);
    }
#pragma unroll
    for (int jj = 0; jj < 8; ++jj) {
      const int d = kg * 128 + jj * 16 + fm;
#pragma unroll
      for (int r = 0; r < 4; ++r)
        ob[(size_t)(qh * 32 + i * 16 + g * 4 + r) * 512 + d] = oacc[i][jj][r] * inv[r];
    }
  }
}

extern "C" void kernel_launch(void* const* d_in, const int* in_sizes, int n_in,
                              void* d_out, int out_size, void* d_ws, size_t ws_size,
                              hipStream_t stream) {
  const float* x  = (const float*)d_in[0];
  const float* Wq = (const float*)d_in[1];
  const float* bq = (const float*)d_in[2];
  const float* Wk = (const float*)d_in[3];
  const float* bk = (const float*)d_in[4];
  const float* Wv = (const float*)d_in[5];
  const float* bv = (const float*)d_in[6];
  float* out = (float*)d_out;

  const size_t SZ = (size_t)16384 * 512 * 2;  // 16.78 MB (half-prec [16384,512])
  char* p = (char*)d_ws;
  unsigned short* xh = (unsigned short*)p; p += SZ;
  unsigned short* Wt = (unsigned short*)p; p += (size_t)3 * 512 * 512 * 2;
  unsigned short* Qb = (unsigned short*)p; p += SZ;              // fp16 [token][512]
  unsigned short* Kb = (unsigned short*)p; p += SZ;              // fp16 [token][512]
  unsigned short* VT = (unsigned short*)p; p += SZ;              // bf16 swizzled V units

  convx_kernel<<<8192, 256, 0, stream>>>(x, xh);
  convw_kernel<<<dim3(16, 16, 3), dim3(32, 8), 0, stream>>>(Wq, Wk, Wv, Wt);
  gemm_qkv_kernel<<<dim3(128, 12), 256, 0, stream>>>(xh, Wt, Qb, Kb, VT, bq, bk, bv);
  attn_fused_kernel<<<256, 512, 0, stream>>>(Qb, Kb, VT, out);
}

// Round 11
// 233.768 us; speedup vs baseline: 1.4077x; 1.0529x over previous
//
#include <hip/hip_runtime.h>

// WordAttention: B=8, S=2048, D_IN=D_H=512, fp32 in/out.
// R17 = R15 attn (PROVEN: 112us, zero scratch) + qkv GEMM upgraded with the
// SAME proven phase engine (single variable; attn byte-identical).
// R16 (ring-3 single-barrier) shelved: two consecutive container failures,
// hang-suspect. R15 base re-adopted.
// qkv before: per k-step {issue 4 gload_lds; __syncthreads (drains vmcnt0);
// compute} = 1-deep blocking pipeline, L2 latency serial on all 16 steps.
// qkv now: ping-pong As/Bs (2x16KB), issue step t+1 BEFORE compute t,
// vmcnt(4) counted wait, raw barrier, compute, lgkmcnt(0)+barrier --
// identical ledger/hazard structure to the attn engine (reuse distance 2,
// trailing barrier separates last-read from next DMA-issue).
// attn numerics/engine unchanged (verified R8-R15): unnormalized p=exp(s)
// bf16 (|s|<~45<<88), no online max; V tiled+swizzled units; 2-barrier
// ping-pong with counted vmcnt(4).

typedef __attribute__((ext_vector_type(8))) _Float16 f16x8;
typedef __attribute__((ext_vector_type(8))) short bf16x8;
typedef __attribute__((ext_vector_type(4))) float f32x4;

__device__ __forceinline__ unsigned short f2h(float f) {
  _Float16 h = (_Float16)f;
  return *(unsigned short*)&h;
}
__device__ __forceinline__ unsigned short f2bf(float f) {
  unsigned int u = __float_as_uint(f);
  unsigned int r = (u + 0x7fffu + ((u >> 16) & 1u)) >> 16;
  return (unsigned short)r;
}
__device__ __forceinline__ float bf2f(unsigned short h) {
  return __uint_as_float(((unsigned int)h) << 16);
}

__device__ __forceinline__ void load_lds16(const void* g, void* l) {
  __builtin_amdgcn_global_load_lds(
      (const __attribute__((address_space(1))) unsigned int*)g,
      (__attribute__((address_space(3))) unsigned int*)l, 16, 0, 0);
}

// ---- x fp32 -> fp16 ----
__global__ __launch_bounds__(256) void convx_kernel(const float* __restrict__ x,
                                                    unsigned short* __restrict__ xh) {
  int i = blockIdx.x * 256 + threadIdx.x;
  float4 v = ((const float4*)x)[i];
  union { unsigned short h[4]; short4 s4; } u;
  u.h[0] = f2h(v.x); u.h[1] = f2h(v.y); u.h[2] = f2h(v.z); u.h[3] = f2h(v.w);
  ((short4*)xh)[i] = u.s4;
}

// ---- W [d][h] fp32 -> Wt [h][d] fp16; z = 0,1,2 selects Wq/Wk/Wv ----
__global__ __launch_bounds__(256) void convw_kernel(
    const float* __restrict__ W0, const float* __restrict__ W1,
    const float* __restrict__ W2, unsigned short* __restrict__ Wt) {
  const float* W = (blockIdx.z == 0) ? W0 : (blockIdx.z == 1) ? W1 : W2;
  unsigned short* t = Wt + (size_t)blockIdx.z * 512 * 512;
  __shared__ float tile[32][33];
  int tx = threadIdx.x, ty = threadIdx.y;  // 32 x 8
  int h0 = blockIdx.x * 32, d0 = blockIdx.y * 32;
  for (int i = ty; i < 32; i += 8) tile[i][tx] = W[(long)(d0 + i) * 512 + h0 + tx];
  __syncthreads();
  for (int i = ty; i < 32; i += 8)
    t[(long)(h0 + i) * 512 + d0 + tx] = f2h(tile[tx][i]);
}

// ---- fused QKV projection: [16384,512] x [512,1536]^T + bias.
//      cols 0..511 -> Qo fp16; 512..1023 -> Ko fp16;
//      1024..1535 -> V tiled+swizzled bf16 (32KB unit = [b][s/32], within:
//      byte L = d*64 + (s%32)*2, stored at L ^ ((d>>1)&7)<<4).
// R17: ping-pong staging + counted vmcnt (was blocking __syncthreads).
__global__ __launch_bounds__(256) void gemm_qkv_kernel(
    const unsigned short* __restrict__ A,   // xh [16384][512] fp16
    const unsigned short* __restrict__ Bt,  // Wt [1536][512] fp16
    unsigned short* __restrict__ Qo, unsigned short* __restrict__ Ko,
    unsigned short* __restrict__ VTo,
    const float* __restrict__ bq, const float* __restrict__ bk,
    const float* __restrict__ bv) {
  __shared__ alignas(16) unsigned short As[2][4096];  // 2 x 8KB ping-pong
  __shared__ alignas(16) unsigned short Bs[2][4096];
  const int t = threadIdx.x;
  const long long bm = (long long)blockIdx.x * 128;
  const long long bn = (long long)blockIdx.y * 128;

  const int ar = t >> 2;
  const int ac = (t & 3) * 8;

  f32x4 acc[4][4];
#pragma unroll
  for (int i = 0; i < 4; i++)
#pragma unroll
    for (int j = 0; j < 4; j++) acc[i][j] = {0.f, 0.f, 0.f, 0.f};

  const int lane = t & 63;
  const int wave = t >> 6;
  const int wm = (wave & 1) * 64;
  const int wn = (wave >> 1) * 64;
  const int fm = lane & 15;
  const int k8 = (lane >> 4) * 8;

  // prologue: step 0 into buf 0 (4 loads in flight)
#pragma unroll
  for (int r = 0; r < 2; r++)
    load_lds16(A + (bm + r * 64 + ar) * 512 + ac, &As[0][r * 2048 + t * 8]);
#pragma unroll
  for (int r = 0; r < 2; r++)
    load_lds16(Bt + (bn + r * 64 + ar) * 512 + ac, &Bs[0][r * 2048 + t * 8]);

  for (int ktt = 0; ktt < 16; ++ktt) {
    const int cur = ktt & 1;
    const int nxt = cur ^ 1;
    if (ktt < 15) {
      const int kc = (ktt + 1) * 32;
#pragma unroll
      for (int r = 0; r < 2; r++)
        load_lds16(A + (bm + r * 64 + ar) * 512 + kc + ac, &As[nxt][r * 2048 + t * 8]);
#pragma unroll
      for (int r = 0; r < 2; r++)
        load_lds16(Bt + (bn + r * 64 + ar) * 512 + kc + ac, &Bs[nxt][r * 2048 + t * 8]);
      asm volatile("s_waitcnt vmcnt(4)" ::: "memory");  // cur landed, nxt in flight
    } else {
      asm volatile("s_waitcnt vmcnt(0)" ::: "memory");
    }
    __builtin_amdgcn_s_barrier();
    __builtin_amdgcn_sched_barrier(0);

    f16x8 af[4], bfr[4];
#pragma unroll
    for (int i = 0; i < 4; i++)
      af[i] = *(const f16x8*)&As[cur][(wm + i * 16 + fm) * 32 + k8];
#pragma unroll
    for (int j = 0; j < 4; j++)
      bfr[j] = *(const f16x8*)&Bs[cur][(wn + j * 16 + fm) * 32 + k8];
    __builtin_amdgcn_s_setprio(1);
#pragma unroll
    for (int i = 0; i < 4; i++)
#pragma unroll
      for (int j = 0; j < 4; j++)
        acc[i][j] = __builtin_amdgcn_mfma_f32_16x16x32_f16(af[i], bfr[j], acc[i][j], 0, 0, 0);
    __builtin_amdgcn_s_setprio(0);
    asm volatile("s_waitcnt lgkmcnt(0)" ::: "memory");  // my frag reads done
    __builtin_amdgcn_s_barrier();                        // buf free for overwrite
  }

  const int crow = (lane >> 4) * 4;  // C/D: col=lane&15, row=(lane>>4)*4+reg
  const int ccol = lane & 15;
#pragma unroll
  for (int j = 0; j < 4; j++) {
    const long long col = bn + wn + j * 16 + ccol;
    float bias = (col < 512) ? bq[col] : (col < 1024) ? bk[col - 512] : bv[col - 1024];
#pragma unroll
    for (int i = 0; i < 4; i++) {
      const long long row0 = bm + wm + i * 16 + crow;
      if (col >= 1024) {
        const long long b = row0 >> 11;
        const long long s = row0 & 2047;
        const long long dcol = col - 1024;
        union { unsigned short h[4]; short4 s4; } u;
#pragma unroll
        for (int r = 0; r < 4; r++) u.h[r] = f2bf(acc[i][j][r] + bias);  // V -> bf16
        // swizzled tiled V: unit=(b,s/32) 32KB; L = d*64+(s%32)*2, XOR'd.
        const long long unit = b * 64 + (s >> 5);
        const int L = ((int)dcol * 64 + (int)(s & 31) * 2) ^ ((((int)dcol >> 1) & 7) << 4);
        *(short4*)((char*)VTo + unit * 32768 + L) = u.s4;
      } else {
        unsigned short* dst = (col < 512) ? (Qo + row0 * 512 + col)
                                          : (Ko + row0 * 512 + (col - 512));
#pragma unroll
        for (int r = 0; r < 4; r++) dst[(size_t)r * 512] = f2h(acc[i][j][r] + bias);
      }
    }
  }
}

// ---- fused attention: out[b][q][d] = (sum_k exp(QK^T) V) / rowsum.
// grid 256 (b=bid&7, q-tile=bid>>3: 64 q-rows), 512 threads (8 waves).
// Wave w: qh=w&1 (32-q half), kg=w>>1 (k-group in QKT / d-quarter in PV).
// BYTE-IDENTICAL to R15 (measured 112us, clean traffic).
__global__ __launch_bounds__(512, 2) void attn_fused_kernel(
    const unsigned short* __restrict__ Qg,  // [8][2048][512] fp16
    const unsigned short* __restrict__ Kg,  // [8][2048][512] fp16
    const unsigned short* __restrict__ Vt,  // [8][64] x 32KB swizzled V units
    float* __restrict__ out) {              // [8][2048][512] fp32
  __shared__ alignas(16) unsigned short SB[2][16384];  // 2x32KB stage ping-pong
  __shared__ alignas(16) unsigned short Qh[16384];     // Q high-d [64q][256d] swz
  __shared__ alignas(16) unsigned short Ps[8192];      // P [64q][128k] bf16 swz
  __shared__ float rsw[4][64];

  const int t = threadIdx.x;
  const int lane = t & 63;
  const int w = t >> 6;
  const int fm = lane & 15;
  const int g = lane >> 4;
  const int qh = w & 1;
  const int kg = w >> 1;
  const int b = blockIdx.x & 7;
  const int q0 = (blockIdx.x >> 3) << 6;

  const unsigned short* Qb = Qg + ((size_t)b * 2048 + q0) * 512;
  const unsigned short* Kb = Kg + (size_t)b * 2048 * 512;
  const unsigned short* Vb = Vt + (size_t)b * 2048 * 512;

  // per-thread staging offsets (4 rounds x 512 thr x 16B = 32KB/unit)
  int ksrc[4], qsrc[4]; unsigned int sdst[4];
#pragma unroll
  for (int r = 0; r < 4; ++r) {
    const int L = r * 8192 + t * 16;  // byte offset within a 32KB unit
    sdst[r] = L >> 1;
    const int kr = L >> 8;            // K unit rows (256 B)
    ksrc[r] = kr * 512 + (((L & 255) ^ ((kr & 7) << 4)) >> 1);
    const int qr = L >> 9;            // Q rows (512 B)
    qsrc[r] = qr * 512 + (((L & 511) ^ ((qr & 7) << 4)) >> 1);
  }

  // ---- prologue: stage Qlow -> SB0, Qhigh -> Qh; read Q-frags (d<256) to regs
#pragma unroll
  for (int r = 0; r < 4; ++r) load_lds16(Qb + qsrc[r], &SB[0][sdst[r]]);
#pragma unroll
  for (int r = 0; r < 4; ++r) load_lds16(Qb + 256 + qsrc[r], &Qh[sdst[r]]);
  asm volatile("s_waitcnt vmcnt(4)" ::: "memory");  // Qlow landed (Qh may fly)
  __builtin_amdgcn_s_barrier();

  const int swz = (fm & 7) << 4;
  const int vswz = ((fm >> 1) & 7) << 4;  // V-read side of the V swizzle
  f16x8 qf[2][8];
#pragma unroll
  for (int j = 0; j < 2; ++j)
#pragma unroll
    for (int ds = 0; ds < 8; ++ds)
      qf[j][ds] = *(const f16x8*)((const char*)SB[0] +
          (qh * 32 + j * 16 + fm) * 512 + ((g * 16 + ds * 64) ^ swz));
  asm volatile("s_waitcnt lgkmcnt(0)" ::: "memory");
  __builtin_amdgcn_s_barrier();
  // stage K-unit0 of kt0 into SB0 (cur of phase 0)
#pragma unroll
  for (int r = 0; r < 4; ++r) load_lds16(Kb + ksrc[r], &SB[0][sdst[r]]);

  f32x4 oacc[2][8];
#pragma unroll
  for (int i = 0; i < 2; ++i)
#pragma unroll
    for (int jj = 0; jj < 8; ++jj) oacc[i][jj] = {0.f, 0.f, 0.f, 0.f};
  float psum0 = 0.f, psum1 = 0.f;
  f32x4 sacc[2][2];

  for (int kt = 0; kt < 16; ++kt) {
    const size_t kbase = (size_t)kt * 65536;  // kt*128*512 elements
#pragma unroll
    for (int u = 0; u < 8; ++u) {
      unsigned short* cur = SB[u & 1];
      unsigned short* nxt = SB[(u & 1) ^ 1];
      // ---- issue next stage unit (1 phase ahead) ----
      if (u < 3) {
#pragma unroll
        for (int r = 0; r < 4; ++r)
          load_lds16(Kb + kbase + (u + 1) * 128 + ksrc[r], &nxt[sdst[r]]);
      } else if (u < 7) {
        const unsigned short* vs = Vb + (size_t)(kt * 4 + (u - 3)) * 16384;
#pragma unroll
        for (int r = 0; r < 4; ++r) load_lds16(vs + sdst[r], &nxt[sdst[r]]);
      } else if (kt < 15) {
#pragma unroll
        for (int r = 0; r < 4; ++r)
          load_lds16(Kb + kbase + 65536 + ksrc[r], &nxt[sdst[r]]);
      }
      // ---- counted wait: cur's 4 loads done, nxt's 4 stay in flight ----
      if (kt == 15 && u == 7)
        asm volatile("s_waitcnt vmcnt(0)" ::: "memory");
      else
        asm volatile("s_waitcnt vmcnt(4)" ::: "memory");
      __builtin_amdgcn_s_barrier();
      __builtin_amdgcn_sched_barrier(0);

      __builtin_amdgcn_s_setprio(1);
      if (u < 4) {
        // ---- QKT phase: S^T[k 32-grp][q 64] += K-unit_u x Q(d-slice) ----
        if (u == 0) {
          sacc[0][0] = {0.f, 0.f, 0.f, 0.f}; sacc[0][1] = {0.f, 0.f, 0.f, 0.f};
          sacc[1][0] = {0.f, 0.f, 0.f, 0.f}; sacc[1][1] = {0.f, 0.f, 0.f, 0.f};
        }
#pragma unroll
        for (int s = 0; s < 4; ++s) {
          const f16x8 a0 = *(const f16x8*)((const char*)cur +
              (kg * 32 + fm) * 256 + ((g * 16 + s * 64) ^ swz));
          const f16x8 a1 = *(const f16x8*)((const char*)cur +
              (kg * 32 + 16 + fm) * 256 + ((g * 16 + s * 64) ^ swz));
          f16x8 b0, b1;
          if (u < 2) {
            b0 = qf[0][u * 4 + s]; b1 = qf[1][u * 4 + s];
          } else {
            const int dz = (g * 16 + ((u - 2) * 4 + s) * 64) ^ swz;
            b0 = *(const f16x8*)((const char*)Qh + (qh * 32 + fm) * 512 + dz);
            b1 = *(const f16x8*)((const char*)Qh + (qh * 32 + 16 + fm) * 512 + dz);
          }
          sacc[0][0] = __builtin_amdgcn_mfma_f32_16x16x32_f16(a0, b0, sacc[0][0], 0, 0, 0);
          sacc[0][1] = __builtin_amdgcn_mfma_f32_16x16x32_f16(a0, b1, sacc[0][1], 0, 0, 0);
          sacc[1][0] = __builtin_amdgcn_mfma_f32_16x16x32_f16(a1, b0, sacc[1][0], 0, 0, 0);
          sacc[1][1] = __builtin_amdgcn_mfma_f32_16x16x32_f16(a1, b1, sacc[1][1], 0, 0, 0);
        }
        if (u == 3) {
          // exp -> bf16 P (swizzled) + rowsum partials
#pragma unroll
          for (int i = 0; i < 2; ++i)
#pragma unroll
            for (int j = 0; j < 2; ++j) {
              const int q = qh * 32 + j * 16 + fm;
              const int k2 = (kg * 32 + i * 16 + g * 4) * 2;
              union { unsigned short h[4]; short4 s4; } uu;
              float s0 = 0.f;
#pragma unroll
              for (int r = 0; r < 4; ++r) {
                const unsigned short pb = f2bf(__expf(sacc[i][j][r]));
                uu.h[r] = pb; s0 += bf2f(pb);
              }
              if (j == 0) psum0 += s0; else psum1 += s0;
              *(short4*)((char*)Ps + q * 256 + (k2 ^ swz)) = uu.s4;
            }
        }
      } else {
        // ---- PV phase: out[q 32-half][d 128-qtr] += P(k-slice) x V-unit ----
        const int ju = u - 4;
        const bf16x8 p0 = *(const bf16x8*)((const char*)Ps +
            (qh * 32 + fm) * 256 + ((ju * 64 + g * 16) ^ swz));
        const bf16x8 p1 = *(const bf16x8*)((const char*)Ps +
            (qh * 32 + 16 + fm) * 256 + ((ju * 64 + g * 16) ^ swz));
#pragma unroll
        for (int jj = 0; jj < 8; ++jj) {
          const bf16x8 vf = *(const bf16x8*)((const char*)cur +
              ((((kg * 128 + jj * 16 + fm) * 64) + g * 16) ^ vswz));
          oacc[0][jj] = __builtin_amdgcn_mfma_f32_16x16x32_bf16(p0, vf, oacc[0][jj], 0, 0, 0);
          oacc[1][jj] = __builtin_amdgcn_mfma_f32_16x16x32_bf16(p1, vf, oacc[1][jj], 0, 0, 0);
        }
      }
      __builtin_amdgcn_s_setprio(0);
      asm volatile("s_waitcnt lgkmcnt(0)" ::: "memory");  // all my LDS reads done
      __builtin_amdgcn_s_barrier();                        // buf free for overwrite
    }
  }

  // ---- rowsum reduce: quads (shuffle) then k-groups (LDS) ----
  psum0 += __shfl_xor(psum0, 16); psum0 += __shfl_xor(psum0, 32);
  psum1 += __shfl_xor(psum1, 16); psum1 += __shfl_xor(psum1, 32);
  if (g == 0) {
    rsw[kg][qh * 32 + fm] = psum0;
    rsw[kg][qh * 32 + 16 + fm] = psum1;
  }
  __syncthreads();

  // ---- normalize + store: row q = qh*32+i*16+g*4+r, col d = kg*128+jj*16+fm
  float* ob = out + ((size_t)b * 2048 + q0) * 512;
#pragma unroll
  for (int i = 0; i < 2; ++i) {
    float inv[4];
#pragma unroll
    for (int r = 0; r < 4; ++r) {
      const int q = qh * 32 + i * 16 + g * 4 + r;
      inv[r] = 1.0f / (rsw[0][q] + rsw[1][q] + rsw[2][q] + rsw[3][q]);
    }
#pragma unroll
    for (int jj = 0; jj < 8; ++jj) {
      const int d = kg * 128 + jj * 16 + fm;
#pragma unroll
      for (int r = 0; r < 4; ++r)
        ob[(size_t)(qh * 32 + i * 16 + g * 4 + r) * 512 + d] = oacc[i][jj][r] * inv[r];
    }
  }
}

extern "C" void kernel_launch(void* const* d_in, const int* in_sizes, int n_in,
                              void* d_out, int out_size, void* d_ws, size_t ws_size,
                              hipStream_t stream) {
  const float* x  = (const float*)d_in[0];
  const float* Wq = (const float*)d_in[1];
  const float* bq = (const float*)d_in[2];
  const float* Wk = (const float*)d_in[3];
  const float* bk = (const float*)d_in[4];
  const float* Wv = (const float*)d_in[5];
  const float* bv = (const float*)d_in[6];
  float* out = (float*)d_out;

  const size_t SZ = (size_t)16384 * 512 * 2;  // 16.78 MB (half-prec [16384,512])
  char* p = (char*)d_ws;
  unsigned short* xh = (unsigned short*)p; p += SZ;
  unsigned short* Wt = (unsigned short*)p; p += (size_t)3 * 512 * 512 * 2;
  unsigned short* Qb = (unsigned short*)p; p += SZ;              // fp16 [token][512]
  unsigned short* Kb = (unsigned short*)p; p += SZ;              // fp16 [token][512]
  unsigned short* VT = (unsigned short*)p; p += SZ;              // bf16 swizzled V units

  convx_kernel<<<8192, 256, 0, stream>>>(x, xh);
  convw_kernel<<<dim3(16, 16, 3), dim3(32, 8), 0, stream>>>(Wq, Wk, Wv, Wt);
  gemm_qkv_kernel<<<dim3(128, 12), 256, 0, stream>>>(xh, Wt, Qb, Kb, VT, bq, bk, bv);
  attn_fused_kernel<<<256, 512, 0, stream>>>(Qb, Kb, VT, out);
}